// Round 4
// baseline (346.429 us; speedup 1.0000x reference)
//
#include <hip/hip_runtime.h>
#include <hip/hip_bf16.h>
#include <stdint.h>

// Problem constants (reference: LoRA adapter forward)
#define TOKENS   8192
#define DIM      4096
#define DIM_OUT  4096
#define LORA_R   16
#define LORA_SCALE 2.0f

typedef __bf16 bf16_t;
typedef __attribute__((ext_vector_type(8))) __bf16 bfrag;   // 8 bf16 = 4 VGPR (MFMA A/B frag)
typedef __attribute__((ext_vector_type(4))) float f32x4;    // MFMA C/D frag

// ---------------------------------------------------------------------------
// async global->LDS, 16B per lane (global_load_lds_dwordx4)
// ---------------------------------------------------------------------------
__device__ __forceinline__ void gload_lds16(const bf16_t* gsrc, bf16_t* ldst) {
    __builtin_amdgcn_global_load_lds(
        (const __attribute__((address_space(1))) uint32_t*)(const void*)gsrc,
        (__attribute__((address_space(3))) uint32_t*)(void*)ldst,
        16, 0, 0);
}

// ---------------------------------------------------------------------------
// Kernel 1: cast x (fp32) -> bf16, 8 elems/thread, grid-stride
// ---------------------------------------------------------------------------
__global__ void cast_x_kernel(const float* __restrict__ x, bf16_t* __restrict__ xb) {
    const int total = TOKENS * DIM / 8;
    for (int i = blockIdx.x * blockDim.x + threadIdx.x; i < total;
         i += gridDim.x * blockDim.x) {
        const float4* p = reinterpret_cast<const float4*>(x + (size_t)i * 8);
        float4 v0 = p[0], v1 = p[1];
        union { bf16_t o[8]; uint4 u; } pk;
        pk.o[0] = (bf16_t)v0.x; pk.o[1] = (bf16_t)v0.y;
        pk.o[2] = (bf16_t)v0.z; pk.o[3] = (bf16_t)v0.w;
        pk.o[4] = (bf16_t)v1.x; pk.o[5] = (bf16_t)v1.y;
        pk.o[6] = (bf16_t)v1.z; pk.o[7] = (bf16_t)v1.w;
        *reinterpret_cast<uint4*>(xb + (size_t)i * 8) = pk.u;
    }
}

// ---------------------------------------------------------------------------
// Kernel 2: Weff_t[n][k] = W[n][k] + SCALE * sum_r A[k][r]*B[r][n], cast bf16.
// ---------------------------------------------------------------------------
__global__ void weff_kernel(const float* __restrict__ W, const float* __restrict__ A,
                            const float* __restrict__ B, bf16_t* __restrict__ Wt) {
    int idx = blockIdx.x * blockDim.x + threadIdx.x;   // DIM_OUT*DIM/32 threads
    int k0 = (idx & 511) << 3;          // 512 k-groups of 8
    int n0 = (idx >> 9) << 2;           // 1024 n-groups of 4

    float bn[4][16];
#pragma unroll
    for (int r = 0; r < 16; ++r) {
        float4 bv = *reinterpret_cast<const float4*>(B + (size_t)r * DIM_OUT + n0);
        bn[0][r] = bv.x; bn[1][r] = bv.y; bn[2][r] = bv.z; bn[3][r] = bv.w;
    }
    float ab[4][8];
#pragma unroll
    for (int j = 0; j < 8; ++j) {
        const float4* ap = reinterpret_cast<const float4*>(A + (size_t)(k0 + j) * LORA_R);
        float4 a0 = ap[0], a1 = ap[1], a2 = ap[2], a3 = ap[3];
        float av[16] = {a0.x,a0.y,a0.z,a0.w,a1.x,a1.y,a1.z,a1.w,
                        a2.x,a2.y,a2.z,a2.w,a3.x,a3.y,a3.z,a3.w};
#pragma unroll
        for (int n = 0; n < 4; ++n) {
            float s = 0.f;
#pragma unroll
            for (int r = 0; r < 16; ++r) s += av[r] * bn[n][r];
            ab[n][j] = s;
        }
    }
#pragma unroll
    for (int n = 0; n < 4; ++n) {
        const float4* wp = reinterpret_cast<const float4*>(W + (size_t)(n0 + n) * DIM + k0);
        float4 w0 = wp[0], w1 = wp[1];
        float wv[8] = {w0.x,w0.y,w0.z,w0.w,w1.x,w1.y,w1.z,w1.w};
        union { bf16_t o[8]; uint4 u; } pk;
#pragma unroll
        for (int j = 0; j < 8; ++j) pk.o[j] = (bf16_t)(wv[j] + LORA_SCALE * ab[n][j]);
        *reinterpret_cast<uint4*>(Wt + (size_t)(n0 + n) * DIM + k0) = pk.u;
    }
}

// ---------------------------------------------------------------------------
// Kernel 3: 256x256 GEMM, faithful m201 8-phase schedule (T1+T2+T3+T4+T5).
// C[m][n] = sum_k Xb[m][k]*Wt[n][k] + bias[n]
// 512 thr = 8 waves (2M x 4N); per-wave 128x64 out = acc[8][4] 16x16 frags.
// LDS: 2 dbuf x (A 256x64 + B 256x64) bf16 = 128 KiB.  Swizzle as round 1/2
// (verified 0 conflicts): linear LDS + inverse-swizzled global src; ds_read
// col = ((ks*4 + (lane>>4)) ^ (lane&7)) * 8.
//
// Per K-tile t (buffer d = t&1), 4 phases; each phase:
//   {ds_reads for THIS phase's MFMA; stage half-tile; s_barrier;
//    lgkmcnt(0)+sched_barrier; setprio(1); 16 MFMA; setprio(0); s_barrier}
// Reads fly during barrier skew; every phase lgkm(0)s its own reads before
// its MFMA -> all waves' reads COMPLETE before the M-barrier (stage safety).
//   P1: read a0-3(d), bLo(d) [12]          | MFMA m0-3 x n0-1
//   P2: read bHi(d) [4];  stage A-H1(t+1)->d^1 | MFMA m0-3 x n2-3
//   P3: read a4-7(d) [8]; stage B-H0(t+2)->d   | MFMA m4-7 x n2-3
//   P4: stage B-H1(t+2), A-H0(t+2)->d; MFMA m4-7 x n0-1; vmcnt(6); bar
// vmcnt(6): outstanding = {A1(t+1), B0(t+2), B1(t+2), A0(t+2)} = 8 gloads;
// wait oldest 2 = A1(t+1) (needed at (t+1).P1); 3 half-tiles stay in flight.
// Region safety: each stage target's last reader lgkm(0)-completed >=2
// barriers before the stage issues (derived per half-tile; see phases).
// ---------------------------------------------------------------------------
#define BM 256
#define BN 256
#define BK 64
#define MB_BLKS (TOKENS / BM)    // 32
#define NB_BLKS (DIM_OUT / BN)   // 16
#define NT      (DIM / BK)       // 64 K-tiles

#define SB0() __builtin_amdgcn_sched_barrier(0)
#define BAR() do { SB0(); __builtin_amdgcn_s_barrier(); SB0(); } while (0)
#define LGKM0() do { asm volatile("s_waitcnt lgkmcnt(0)" ::: "memory"); SB0(); } while (0)
#define VMWAIT_(n) asm volatile("s_waitcnt vmcnt(" #n ")" ::: "memory")
#define VMWAIT(n) VMWAIT_(n)

__global__ __launch_bounds__(512, 2) void gemm_kernel(
    const bf16_t* __restrict__ Xb, const bf16_t* __restrict__ Wt,
    const float* __restrict__ bias, float* __restrict__ C)
{
    __shared__ __align__(16) bf16_t sA[2][BM][BK];   // 64 KiB
    __shared__ __align__(16) bf16_t sB[2][BN][BK];   // 64 KiB

    const int nwg = MB_BLKS * NB_BLKS;               // 512, %8==0 -> bijective
    int bid = blockIdx.x;
    int swz = (bid & 7) * (nwg >> 3) + (bid >> 3);   // XCD-aware remap
    int bm = swz / NB_BLKS;
    int bn = swz % NB_BLKS;

    const int tid  = threadIdx.x;
    const int lane = tid & 63;
    const int wid  = tid >> 6;       // 0..7
    const int wr   = wid >> 2;       // 0..1  (M half)
    const int wc   = wid & 3;        // 0..3  (N quarter)

    // ---- staging constants (linear LDS dest, pre-swizzled global src) ----
    const int srow = tid >> 3;                       // 0..63
    const int scol = (tid & 7) * 8;                  // linear col (elems)
    const int koff = (((tid & 7) ^ ((tid >> 3) & 7)) * 8); // swizzled src col
    const bf16_t* Ag = Xb + (size_t)(bm * BM + srow) * DIM + koff;
    const bf16_t* Bg = Wt + (size_t)(bn * BN + srow) * DIM + koff;

// stage half h (rows h*128 .. h*128+127) of A/B k-tile kt into buffer dd
// (2 x gload_lds16 per thread = 16 KiB)
#define STAGE_A_H(dd, kt, h) do { \
    const bf16_t* s_ = Ag + (size_t)(kt) * BK + (size_t)((h) * 128) * DIM; \
    bf16_t* d_ = &sA[dd][(h) * 128 + srow][scol]; \
    gload_lds16(s_,                    d_); \
    gload_lds16(s_ + (size_t)64 * DIM, d_ + 64 * BK); \
} while (0)

#define STAGE_B_H(dd, kt, h) do { \
    const bf16_t* s_ = Bg + (size_t)(kt) * BK + (size_t)((h) * 128) * DIM; \
    bf16_t* d_ = &sB[dd][(h) * 128 + srow][scol]; \
    gload_lds16(s_,                    d_); \
    gload_lds16(s_ + (size_t)64 * DIM, d_ + 64 * BK); \
} while (0)

    // ---- fragment-read constants (swizzled) ----
    const int q     = lane & 7;
    const int kslot = lane >> 4;                     // 0..3
    const int r15   = lane & 15;
    const int cK0   = ((kslot    ) ^ q) * 8;         // ks=0 col (elems)
    const int cK1   = ((kslot + 4) ^ q) * 8;         // ks=1 col (elems)
    const int arow0 = wr * 128 + r15;                // + m*16
    const int brow0 = wc * 64  + r15;                // + n*16

    f32x4 acc[8][4] = {};
    bfrag a[4][2], bLo[2][2], bHi[2][2];

#define READ_A4(dst, dd, mb) do { \
    _Pragma("unroll") \
    for (int m_ = 0; m_ < 4; ++m_) { \
        dst[m_][0] = *reinterpret_cast<const bfrag*>(&sA[dd][arow0 + (mb + m_) * 16][cK0]); \
        dst[m_][1] = *reinterpret_cast<const bfrag*>(&sA[dd][arow0 + (mb + m_) * 16][cK1]); \
    } \
} while (0)

#define READ_B2(dst, dd, nb) do { \
    _Pragma("unroll") \
    for (int n_ = 0; n_ < 2; ++n_) { \
        dst[n_][0] = *reinterpret_cast<const bfrag*>(&sB[dd][brow0 + (nb + n_) * 16][cK0]); \
        dst[n_][1] = *reinterpret_cast<const bfrag*>(&sB[dd][brow0 + (nb + n_) * 16][cK1]); \
    } \
} while (0)

#define MFMA_Q(Af, Bf, mb, nb) do { \
    __builtin_amdgcn_s_setprio(1); \
    _Pragma("unroll") \
    for (int m_ = 0; m_ < 4; ++m_) \
    _Pragma("unroll") \
    for (int n_ = 0; n_ < 2; ++n_) \
    _Pragma("unroll") \
    for (int ks_ = 0; ks_ < 2; ++ks_) \
        acc[mb + m_][nb + n_] = __builtin_amdgcn_mfma_f32_16x16x32_bf16( \
            Af[m_][ks_], Bf[n_][ks_], acc[mb + m_][nb + n_], 0, 0, 0); \
    __builtin_amdgcn_s_setprio(0); \
} while (0)

// One K-tile (buffer d). S1: stage A-H1(kt+1) -> d^1. S2: stage B/A(kt+2) -> d.
// VM: vmcnt immediate at the tile-end wait.
#define TILE(d, kt, S1, S2, VM) do { \
    /* P1 */ READ_A4(a, d, 0); READ_B2(bLo, d, 0); \
             BAR(); LGKM0(); MFMA_Q(a, bLo, 0, 0); BAR(); \
    /* P2 */ READ_B2(bHi, d, 2); \
             if (S1) STAGE_A_H((d) ^ 1, (kt) + 1, 1); \
             BAR(); LGKM0(); MFMA_Q(a, bHi, 0, 2); BAR(); \
    /* P3 */ READ_A4(a, d, 4); \
             if (S2) STAGE_B_H(d, (kt) + 2, 0); \
             BAR(); LGKM0(); MFMA_Q(a, bHi, 4, 2); BAR(); \
    /* P4 */ if (S2) { STAGE_B_H(d, (kt) + 2, 1); STAGE_A_H(d, (kt) + 2, 0); } \
             BAR(); MFMA_Q(a, bLo, 4, 0); VMWAIT(VM); BAR(); \
} while (0)

    // ---- prologue: tile0 fully + tile1 {A0,B0,B1} (A1(1) comes at 0.P2) ----
    STAGE_A_H(0, 0, 0); STAGE_A_H(0, 0, 1); STAGE_B_H(0, 0, 0); STAGE_B_H(0, 0, 1);
    STAGE_A_H(1, 1, 0); STAGE_B_H(1, 1, 0); STAGE_B_H(1, 1, 1);
    VMWAIT(6);          // 14 gloads out; land tile0's 8; tile1's 6 in flight
    BAR();

    // ---- main loop: tiles 0..61 (31 iterations x 2) ----
    for (int it = 0; it < NT / 2 - 1; ++it) {
        int kt0 = 2 * it;
        TILE(0, kt0,     true, true, 6);
        TILE(1, kt0 + 1, true, true, 6);
    }
    // ---- peeled tiles 62, 63 ----
    TILE(0, 62, true,  false, 0);   // still stages A-H1(63); drains at P4
    TILE(1, 63, false, false, 0);

    // ---- epilogue: D layout row=(lane>>4)*4+j, col=lane&15 ----
    int row0 = bm * BM + wr * 128 + (lane >> 4) * 4;
    int col0 = bn * BN + wc * 64 + r15;
#pragma unroll
    for (int n = 0; n < 4; ++n) {
        int c = col0 + n * 16;
        float bv = bias[c];
#pragma unroll
        for (int m = 0; m < 8; ++m) {
            int r = row0 + m * 16;
#pragma unroll
            for (int j = 0; j < 4; ++j)
                C[(size_t)(r + j) * DIM_OUT + c] = acc[m][n][j] + bv;
        }
    }
}

// ---------------------------------------------------------------------------
extern "C" void kernel_launch(void* const* d_in, const int* in_sizes, int n_in,
                              void* d_out, int out_size, void* d_ws, size_t ws_size,
                              hipStream_t stream) {
    const float* x = (const float*)d_in[0];
    const float* A = (const float*)d_in[1];
    const float* B = (const float*)d_in[2];
    const float* W = (const float*)d_in[3];
    const float* b = (const float*)d_in[4];
    float* out = (float*)d_out;

    // workspace: xb (8192*4096 bf16 = 64MB) | Wt (4096*4096 bf16 = 32MB)
    bf16_t* xb = (bf16_t*)d_ws;
    bf16_t* Wt = (bf16_t*)((char*)d_ws + (size_t)TOKENS * DIM * 2);

    cast_x_kernel<<<2048, 256, 0, stream>>>(x, xb);
    weff_kernel<<<(DIM_OUT * DIM / 32) / 256, 256, 0, stream>>>(W, A, B, Wt);
    gemm_kernel<<<MB_BLKS * NB_BLKS, 512, 0, stream>>>(xb, Wt, b, out);
}